// Round 4
// baseline (384.084 us; speedup 1.0000x reference)
//
#include <hip/hip_runtime.h>
#include <hip/hip_bf16.h>
#include <stdint.h>

#define IN_F   4096
#define OUT_F  4096
#define BATCH  4096

typedef __bf16 bf16x8_t __attribute__((ext_vector_type(8)));
typedef float  f32x4_t  __attribute__((ext_vector_type(4)));
typedef float  f32x4v   __attribute__((ext_vector_type(4)));   // for nontemporal builtins
typedef unsigned short u16x4v __attribute__((ext_vector_type(4)));

#define AS_GLOBAL(p) ((const __attribute__((address_space(1))) void*)(p))
#define AS_LDS(p)    ((__attribute__((address_space(3))) void*)(p))

__device__ __forceinline__ unsigned short f32_to_bf16_rne(float f) {
    union { float f; uint32_t u; } v; v.f = f;
    uint32_t u = v.u;
    u += 0x7FFFu + ((u >> 16) & 1u);
    return (unsigned short)(u >> 16);
}

// ---------------------------------------------------------------------------
// Pre-pass: xb = bf16(x), wb = bf16(W * M). 8192 blocks x 256 thr x 2 float4s.
// Inputs are single-use -> nontemporal loads; outputs feed gemm -> normal.
// ---------------------------------------------------------------------------
__global__ __launch_bounds__(256)
void convert_kernel(const float* __restrict__ x,
                    const float* __restrict__ w,
                    const float* __restrict__ m,
                    unsigned short* __restrict__ xb,
                    unsigned short* __restrict__ wb) {
    const int64_t i0 = (int64_t)blockIdx.x * 512 + threadIdx.x;
#pragma unroll
    for (int u = 0; u < 2; ++u) {
        const int64_t i = i0 + u * 256;
        f32x4v xv = __builtin_nontemporal_load(&((const f32x4v*)x)[i]);
        f32x4v wv = __builtin_nontemporal_load(&((const f32x4v*)w)[i]);
        f32x4v mv = __builtin_nontemporal_load(&((const f32x4v*)m)[i]);
        u16x4v xo, wo;
        xo.x = f32_to_bf16_rne(xv.x);
        xo.y = f32_to_bf16_rne(xv.y);
        xo.z = f32_to_bf16_rne(xv.z);
        xo.w = f32_to_bf16_rne(xv.w);
        wo.x = f32_to_bf16_rne(wv.x * mv.x);
        wo.y = f32_to_bf16_rne(wv.y * mv.y);
        wo.z = f32_to_bf16_rne(wv.z * mv.z);
        wo.w = f32_to_bf16_rne(wv.w * mv.w);
        ((u16x4v*)xb)[i] = xo;
        ((u16x4v*)wb)[i] = wo;
    }
}

// ---------------------------------------------------------------------------
// bf16 MFMA GEMM: y[b][o] = sum_k xb[b][k]*wb[o][k] + bias[o]
// BM=256, BN=128, BK=64; 256 threads = 4 waves in 2x2; wave tile 128x64 via
// 8x4 frags of 16x16x32 MFMA (higher LDS reuse: 21.8 MAC/LDS-byte).
// XOR-swizzled staging (global-side) keeps frag ds_read_b128 conflict-free.
// Pipeline: read all ks=1 frags -> barrier -> issue next tile glds -> MFMA
// (overlaps the glds flight) -> drain barrier.
// ---------------------------------------------------------------------------
#define BM 256
#define BN 128
#define BK 64

__global__ __launch_bounds__(256)
void gemm_bt_bias_kernel(const unsigned short* __restrict__ A,   // [BATCH][IN_F]
                         const unsigned short* __restrict__ B,   // [OUT_F][IN_F]
                         const float* __restrict__ bias,         // [OUT_F]
                         float* __restrict__ C) {                // [BATCH][OUT_F]
    __shared__ __align__(16) unsigned short sA[BM * BK];  // 32 KiB
    __shared__ __align__(16) unsigned short sB[BN * BK];  // 16 KiB

    const int t    = threadIdx.x;
    const int wv   = t >> 6;
    const int lane = t & 63;
    const int quad = lane >> 4;    // 0..3
    const int l16  = lane & 15;

    const int bm = blockIdx.y * BM;
    const int bn = blockIdx.x * BN;

    const int wr = wv >> 1;        // 0..1 -> 128-row half
    const int wc = wv & 1;         // 0..1 -> 64-col half

    // Staging: per round r, thread t loads 16 B at row r*32 + t/8,
    // elem-col 8*((t&7)^((t>>3)&7))  [chunk XOR-swizzled by row&7].
    // LDS linear offset = r*4096 + t*16 (matches glds wave-uniform+lane*16).
    const int srow = t >> 3;
    const int scol = 8 * ((t & 7) ^ ((t >> 3) & 7));
    const unsigned short* gA = A + (int64_t)(bm + srow) * IN_F + scol;
    const unsigned short* gB = B + (int64_t)(bn + srow) * IN_F + scol;

#define ISSUE_TILE(k0)                                                        \
    do {                                                                      \
        _Pragma("unroll")                                                     \
        for (int r = 0; r < 8; ++r)                                           \
            __builtin_amdgcn_global_load_lds(                                 \
                AS_GLOBAL(gA + (int64_t)r * 32 * IN_F + (k0)),                \
                AS_LDS((char*)sA + r * 4096 + wv * 1024 + lane * 16), 16, 0, 0); \
        _Pragma("unroll")                                                     \
        for (int r = 0; r < 4; ++r)                                           \
            __builtin_amdgcn_global_load_lds(                                 \
                AS_GLOBAL(gB + (int64_t)r * 32 * IN_F + (k0)),                \
                AS_LDS((char*)sB + r * 4096 + wv * 1024 + lane * 16), 16, 0, 0); \
    } while (0)

    f32x4_t acc[8][4];
#pragma unroll
    for (int mi = 0; mi < 8; ++mi)
#pragma unroll
        for (int ni = 0; ni < 4; ++ni)
            acc[mi][ni] = (f32x4_t){0.f, 0.f, 0.f, 0.f};

    ISSUE_TILE(0);

    for (int k0 = 0; k0 < IN_F; k0 += BK) {
        __syncthreads();   // drain: tile-k staging loads complete & visible

        // ---- ks = 0: streamed (1 live A-frag) ----
        bf16x8_t bf0[4];
#pragma unroll
        for (int ni = 0; ni < 4; ++ni) {
            const int row = wc * 64 + ni * 16 + l16;
            bf0[ni] = *(const bf16x8_t*)(sB + row * BK + (quad ^ (row & 7)) * 8);
        }
#pragma unroll
        for (int mi = 0; mi < 8; ++mi) {
            const int row = wr * 128 + mi * 16 + l16;
            bf16x8_t af = *(const bf16x8_t*)(sA + row * BK + (quad ^ (row & 7)) * 8);
#pragma unroll
            for (int ni = 0; ni < 4; ++ni)
                acc[mi][ni] = __builtin_amdgcn_mfma_f32_16x16x32_bf16(
                    af, bf0[ni], acc[mi][ni], 0, 0, 0);
        }

        // ---- ks = 1: load all frags to regs, then free the LDS buffer ----
        bf16x8_t bf1[4], af1[8];
#pragma unroll
        for (int ni = 0; ni < 4; ++ni) {
            const int row = wc * 64 + ni * 16 + l16;
            bf1[ni] = *(const bf16x8_t*)(sB + row * BK + ((4 + quad) ^ (row & 7)) * 8);
        }
#pragma unroll
        for (int mi = 0; mi < 8; ++mi) {
            const int row = wr * 128 + mi * 16 + l16;
            af1[mi] = *(const bf16x8_t*)(sA + row * BK + ((4 + quad) ^ (row & 7)) * 8);
        }

        __syncthreads();   // all waves done reading tile k -> safe to overwrite

        if (k0 + BK < IN_F)
            ISSUE_TILE(k0 + BK);   // next tile's loads fly during the MFMAs below

#pragma unroll
        for (int mi = 0; mi < 8; ++mi)
#pragma unroll
            for (int ni = 0; ni < 4; ++ni)
                acc[mi][ni] = __builtin_amdgcn_mfma_f32_16x16x32_bf16(
                    af1[mi], bf1[ni], acc[mi][ni], 0, 0, 0);
    }

    // Epilogue: C/D layout col = lane&15 (n), row = quad*4 + reg (m).
    float bv[4];
#pragma unroll
    for (int ni = 0; ni < 4; ++ni)
        bv[ni] = bias[bn + wc * 64 + ni * 16 + l16];

#pragma unroll
    for (int mi = 0; mi < 8; ++mi) {
        const int row0 = bm + wr * 128 + mi * 16 + quad * 4;
#pragma unroll
        for (int ni = 0; ni < 4; ++ni) {
            const int col = bn + wc * 64 + ni * 16 + l16;
#pragma unroll
            for (int reg = 0; reg < 4; ++reg)
                C[(int64_t)(row0 + reg) * OUT_F + col] = acc[mi][ni][reg] + bv[ni];
        }
    }
#undef ISSUE_TILE
}

// ---------------------------------------------------------------------------
// Fallback (workspace too small): plain fp32 tiled GEMM.
// ---------------------------------------------------------------------------
__global__ void fallback_gemm_kernel(const float* __restrict__ x,
                                     const float* __restrict__ w,
                                     const float* __restrict__ bias,
                                     const float* __restrict__ m,
                                     float* __restrict__ y) {
    __shared__ float sx[16][17];
    __shared__ float sw[16][17];
    const int tx = threadIdx.x, ty = threadIdx.y;
    const int row = blockIdx.y * 16 + ty;
    const int col = blockIdx.x * 16 + tx;
    float acc = 0.f;
    for (int k0 = 0; k0 < IN_F; k0 += 16) {
        sx[ty][tx] = x[(int64_t)row * IN_F + k0 + tx];
        const int64_t widx = (int64_t)(blockIdx.x * 16 + ty) * IN_F + k0 + tx;
        sw[ty][tx] = w[widx] * m[widx];
        __syncthreads();
#pragma unroll
        for (int kk = 0; kk < 16; ++kk)
            acc += sx[ty][kk] * sw[tx][kk];
        __syncthreads();
    }
    y[(int64_t)row * OUT_F + col] = acc + bias[col];
}

// ---------------------------------------------------------------------------
extern "C" void kernel_launch(void* const* d_in, const int* in_sizes, int n_in,
                              void* d_out, int out_size, void* d_ws, size_t ws_size,
                              hipStream_t stream) {
    const float* x    = (const float*)d_in[0];
    const float* w    = (const float*)d_in[1];
    const float* bias = (const float*)d_in[2];
    const float* m    = (const float*)d_in[3];
    float* y = (float*)d_out;

    const size_t need = (size_t)2 * (size_t)OUT_F * (size_t)IN_F * sizeof(unsigned short);

    if (ws_size >= need) {
        unsigned short* xb = (unsigned short*)d_ws;
        unsigned short* wb = xb + (size_t)BATCH * IN_F;

        convert_kernel<<<8192, 256, 0, stream>>>(x, w, m, xb, wb);

        dim3 grid(OUT_F / BN, BATCH / BM);   // 32 x 16 = 512 blocks
        gemm_bt_bias_kernel<<<grid, 256, 0, stream>>>(xb, wb, bias, y);
    } else {
        dim3 grid(OUT_F / 16, BATCH / 16);
        dim3 block(16, 16);
        fallback_gemm_kernel<<<grid, block, 0, stream>>>(x, w, bias, m, y);
    }
}

// Round 5
// 324.653 us; speedup vs baseline: 1.1831x; 1.1831x over previous
//
#include <hip/hip_runtime.h>
#include <hip/hip_bf16.h>
#include <stdint.h>

#define IN_F   4096
#define OUT_F  4096
#define BATCH  4096

typedef __bf16 bf16x8_t __attribute__((ext_vector_type(8)));
typedef float  f32x4_t  __attribute__((ext_vector_type(4)));
typedef float  f32x4v   __attribute__((ext_vector_type(4)));
typedef unsigned short u16x4v __attribute__((ext_vector_type(4)));

#define AS_GLOBAL(p) ((const __attribute__((address_space(1))) void*)(p))
#define AS_LDS(p)    ((__attribute__((address_space(3))) void*)(p))

__device__ __forceinline__ unsigned short f32_to_bf16_rne(float f) {
    union { float f; uint32_t u; } v; v.f = f;
    uint32_t u = v.u;
    u += 0x7FFFu + ((u >> 16) & 1u);
    return (unsigned short)(u >> 16);
}

// ---------------------------------------------------------------------------
// Pre-pass: xb = bf16(x), wb = bf16(W * M). 8192 blocks x 256 thr x 2 float4s.
// Inputs are single-use -> nontemporal loads.
// ---------------------------------------------------------------------------
__global__ __launch_bounds__(256)
void convert_kernel(const float* __restrict__ x,
                    const float* __restrict__ w,
                    const float* __restrict__ m,
                    unsigned short* __restrict__ xb,
                    unsigned short* __restrict__ wb) {
    const int64_t i0 = (int64_t)blockIdx.x * 512 + threadIdx.x;
#pragma unroll
    for (int u = 0; u < 2; ++u) {
        const int64_t i = i0 + u * 256;
        f32x4v xv = __builtin_nontemporal_load(&((const f32x4v*)x)[i]);
        f32x4v wv = __builtin_nontemporal_load(&((const f32x4v*)w)[i]);
        f32x4v mv = __builtin_nontemporal_load(&((const f32x4v*)m)[i]);
        u16x4v xo, wo;
        xo.x = f32_to_bf16_rne(xv.x);
        xo.y = f32_to_bf16_rne(xv.y);
        xo.z = f32_to_bf16_rne(xv.z);
        xo.w = f32_to_bf16_rne(xv.w);
        wo.x = f32_to_bf16_rne(wv.x * mv.x);
        wo.y = f32_to_bf16_rne(wv.y * mv.y);
        wo.z = f32_to_bf16_rne(wv.z * mv.z);
        wo.w = f32_to_bf16_rne(wv.w * mv.w);
        ((u16x4v*)xb)[i] = xo;
        ((u16x4v*)wb)[i] = wo;
    }
}

// ---------------------------------------------------------------------------
// bf16 MFMA GEMM: y[b][o] = sum_k xb[b][k]*wb[o][k] + bias[o]
// BM=BN=128, BK=64 (round-2 proven config), now DOUBLE-BUFFERED with ONE
// barrier per K-iteration: prefetch glds into buf^1 issued at top of iter i,
// drained by iter i+1's barrier -> flight window = whole tile compute.
// XOR swizzle (global-side) keeps frag ds_read_b128 conflict-free.
// ---------------------------------------------------------------------------
#define BM 128
#define BN 128
#define BK 64

__global__ __launch_bounds__(256)
void gemm_bt_bias_kernel(const unsigned short* __restrict__ A,   // [BATCH][IN_F]
                         const unsigned short* __restrict__ B,   // [OUT_F][IN_F]
                         const float* __restrict__ bias,         // [OUT_F]
                         float* __restrict__ C) {                // [BATCH][OUT_F]
    __shared__ __align__(16) unsigned short sA[2][BM * BK];  // 2 x 16 KiB
    __shared__ __align__(16) unsigned short sB[2][BN * BK];  // 2 x 16 KiB

    const int t    = threadIdx.x;
    const int wv   = t >> 6;
    const int lane = t & 63;
    const int quad = lane >> 4;    // 0..3
    const int l16  = lane & 15;

    const int bm = blockIdx.y * BM;
    const int bn = blockIdx.x * BN;

    const int wr = wv >> 1;
    const int wc = wv & 1;

    // Staging: per round r of 4, thread t loads 16 B for
    //   row = r*32 + t/8, elem-col = 8*((t&7)^((t>>3)&7))  [swizzled by row&7]
    // landing at LDS linear byte offset r*4096 + t*16.
    const int srow = t >> 3;
    const int scol = 8 * ((t & 7) ^ ((t >> 3) & 7));
    const unsigned short* gA = A + (int64_t)(bm + srow) * IN_F + scol;
    const unsigned short* gB = B + (int64_t)(bn + srow) * IN_F + scol;

#define ISSUE_TILE(buf, k0)                                                   \
    do {                                                                      \
        _Pragma("unroll")                                                     \
        for (int r = 0; r < 4; ++r) {                                         \
            __builtin_amdgcn_global_load_lds(                                 \
                AS_GLOBAL(gA + (int64_t)r * 32 * IN_F + (k0)),                \
                AS_LDS((char*)sA[buf] + r * 4096 + wv * 1024 + lane * 16), 16, 0, 0); \
            __builtin_amdgcn_global_load_lds(                                 \
                AS_GLOBAL(gB + (int64_t)r * 32 * IN_F + (k0)),                \
                AS_LDS((char*)sB[buf] + r * 4096 + wv * 1024 + lane * 16), 16, 0, 0); \
        }                                                                     \
    } while (0)

    f32x4_t acc[4][4];
#pragma unroll
    for (int mi = 0; mi < 4; ++mi)
#pragma unroll
        for (int ni = 0; ni < 4; ++ni)
            acc[mi][ni] = (f32x4_t){0.f, 0.f, 0.f, 0.f};

    ISSUE_TILE(0, 0);

    int buf = 0;
    for (int k0 = 0; k0 < IN_F; k0 += BK, buf ^= 1) {
        // One barrier per iter: (a) drains glds into sA/sB[buf] (issued last
        // iter; vmcnt(0) before s_barrier), (b) all waves done reading
        // sA/sB[buf^1] -> safe to overwrite with the prefetch below.
        __syncthreads();

        if (k0 + BK < IN_F)
            ISSUE_TILE(buf ^ 1, k0 + BK);   // flies across the whole compute below

        const unsigned short* __restrict__ cA = sA[buf];
        const unsigned short* __restrict__ cB = sB[buf];

#pragma unroll
        for (int ks = 0; ks < 2; ++ks) {
            bf16x8_t af[4], bf[4];
#pragma unroll
            for (int mi = 0; mi < 4; ++mi) {
                const int row = wr * 64 + mi * 16 + l16;
                const int ch  = (ks * 4 + quad) ^ (row & 7);
                af[mi] = *(const bf16x8_t*)(cA + row * BK + ch * 8);
            }
#pragma unroll
            for (int ni = 0; ni < 4; ++ni) {
                const int row = wc * 64 + ni * 16 + l16;
                const int ch  = (ks * 4 + quad) ^ (row & 7);
                bf[ni] = *(const bf16x8_t*)(cB + row * BK + ch * 8);
            }
#pragma unroll
            for (int mi = 0; mi < 4; ++mi)
#pragma unroll
                for (int ni = 0; ni < 4; ++ni)
                    acc[mi][ni] = __builtin_amdgcn_mfma_f32_16x16x32_bf16(
                        af[mi], bf[ni], acc[mi][ni], 0, 0, 0);
        }
    }

    // Epilogue: C/D layout col = lane&15 (n), row = quad*4 + reg (m).
    float bv[4];
#pragma unroll
    for (int ni = 0; ni < 4; ++ni)
        bv[ni] = bias[bn + wc * 64 + ni * 16 + l16];

#pragma unroll
    for (int mi = 0; mi < 4; ++mi) {
        const int row0 = bm + wr * 64 + mi * 16 + quad * 4;
#pragma unroll
        for (int ni = 0; ni < 4; ++ni) {
            const int col = bn + wc * 64 + ni * 16 + l16;
#pragma unroll
            for (int reg = 0; reg < 4; ++reg)
                C[(int64_t)(row0 + reg) * OUT_F + col] = acc[mi][ni][reg] + bv[ni];
        }
    }
#undef ISSUE_TILE
}

// ---------------------------------------------------------------------------
// Fallback (workspace too small): plain fp32 tiled GEMM.
// ---------------------------------------------------------------------------
__global__ void fallback_gemm_kernel(const float* __restrict__ x,
                                     const float* __restrict__ w,
                                     const float* __restrict__ bias,
                                     const float* __restrict__ m,
                                     float* __restrict__ y) {
    __shared__ float sx[16][17];
    __shared__ float sw[16][17];
    const int tx = threadIdx.x, ty = threadIdx.y;
    const int row = blockIdx.y * 16 + ty;
    const int col = blockIdx.x * 16 + tx;
    float acc = 0.f;
    for (int k0 = 0; k0 < IN_F; k0 += 16) {
        sx[ty][tx] = x[(int64_t)row * IN_F + k0 + tx];
        const int64_t widx = (int64_t)(blockIdx.x * 16 + ty) * IN_F + k0 + tx;
        sw[ty][tx] = w[widx] * m[widx];
        __syncthreads();
#pragma unroll
        for (int kk = 0; kk < 16; ++kk)
            acc += sx[ty][kk] * sw[tx][kk];
        __syncthreads();
    }
    y[(int64_t)row * OUT_F + col] = acc + bias[col];
}

// ---------------------------------------------------------------------------
extern "C" void kernel_launch(void* const* d_in, const int* in_sizes, int n_in,
                              void* d_out, int out_size, void* d_ws, size_t ws_size,
                              hipStream_t stream) {
    const float* x    = (const float*)d_in[0];
    const float* w    = (const float*)d_in[1];
    const float* bias = (const float*)d_in[2];
    const float* m    = (const float*)d_in[3];
    float* y = (float*)d_out;

    const size_t need = (size_t)2 * (size_t)OUT_F * (size_t)IN_F * sizeof(unsigned short);

    if (ws_size >= need) {
        unsigned short* xb = (unsigned short*)d_ws;
        unsigned short* wb = xb + (size_t)BATCH * IN_F;

        convert_kernel<<<8192, 256, 0, stream>>>(x, w, m, xb, wb);

        dim3 grid(OUT_F / BN, BATCH / BM);   // 32 x 32 = 1024 blocks
        gemm_bt_bias_kernel<<<grid, 256, 0, stream>>>(xb, wb, bias, y);
    } else {
        dim3 grid(OUT_F / 16, BATCH / 16);
        dim3 block(16, 16);
        fallback_gemm_kernel<<<grid, block, 0, stream>>>(x, w, bias, m, y);
    }
}